// Round 5
// baseline (623.821 us; speedup 1.0000x reference)
//
#include <hip/hip_runtime.h>
#include <hip/hip_bf16.h>
#include <cstdint>

#define S 8
#define NTOT 20000
#define NSUB 4000
#define F 128
#define HID 64
#define NH 8
#define DH 8

typedef __attribute__((ext_vector_type(8))) short bf16x8;
typedef __attribute__((ext_vector_type(4))) short bf16x4;
typedef __attribute__((ext_vector_type(4))) float f32x4;

__device__ __forceinline__ short f2bf(float f) {
  union { __hip_bfloat16 h; short s; } u;
  u.h = __float2bfloat16(f);
  return u.s;
}

// ---------------- position map
__global__ void k_pos_init(int* __restrict__ posIdx) {
  int t = blockIdx.x * 256 + threadIdx.x;
  if (t < NTOT * S) posIdx[t] = -1;
}

__global__ void k_pos_scatter(const int* __restrict__ nodes, int* __restrict__ posIdx) {
  int t = blockIdx.x * 256 + threadIdx.x;
  if (t < S * NSUB) {
    int s = t / NSUB, i = t - s * NSUB;
    posIdx[nodes[t] * S + s] = i;
  }
}

// ---------------- Pt1 = (emb[nodes] @ W1)^T bf16, 16 rows/block, 8B-granule writes
__global__ __launch_bounds__(256) void k_feat_w1(const int* __restrict__ nodes,
                                                 const float* __restrict__ emb,
                                                 const float* __restrict__ W1,
                                                 short* __restrict__ Pt) {
  __shared__ __align__(16) float feat[16][F];
  __shared__ float tr[64][17];
  int t = threadIdx.x;
  int s = blockIdx.x / 250;
  int i0 = (blockIdx.x - s * 250) * 16;
  int gr0 = blockIdx.x * 16;
  int lr = t >> 4, lc = (t & 15) * 8;
  int n = nodes[gr0 + lr];
  *(f32x4*)&feat[lr][lc]     = *(const f32x4*)(emb + (size_t)n * F + lc);
  *(f32x4*)&feat[lr][lc + 4] = *(const f32x4*)(emb + (size_t)n * F + lc + 4);
  __syncthreads();
  int j = t & 63, ig = t >> 6;
  float acc[4] = {0.f, 0.f, 0.f, 0.f};
  for (int k = 0; k < F; ++k) {
    float w = W1[k * HID + j];
    #pragma unroll
    for (int i = 0; i < 4; ++i) acc[i] += feat[ig * 4 + i][k] * w;
  }
  #pragma unroll
  for (int i = 0; i < 4; ++i) tr[j][ig * 4 + i] = acc[i];
  __syncthreads();
  int jr = t >> 2, seg = (t & 3) * 4;
  bf16x4 o;
  #pragma unroll
  for (int u = 0; u < 4; ++u) o[u] = f2bf(tr[jr][seg + u]);
  *(bf16x4*)(Pt + ((size_t)s * HID + jr) * NSUB + i0 + seg) = o;
}

// ---------------- adj GEMM (fp32 adj, bf16 MFMA), split-K x4, XCD-snapshot swizzle
// grid 1024: s=bid&7 (XCD), t=bid>>3: z=t&3, mb=t>>2. block 256 = 4 waves; wave = 32 rows.
__global__ __launch_bounds__(256) void k_adj(const float* __restrict__ adj,
                                             const short* __restrict__ Pt,
                                             float* __restrict__ part) {
  int bid = blockIdx.x;
  int s = bid & 7;
  int t = bid >> 3;
  int z = t & 3, mb = t >> 2;
  int ks_ = z << 10;
  int ke_ = (z == 3) ? NSUB : ks_ + 1024;
  int wave = threadIdx.x >> 6, lane = threadIdx.x & 63;
  int l15 = lane & 15, g = lane >> 4;
  int m0 = mb * 128 + wave * 32;
  int r0 = m0 + l15, r1 = m0 + 16 + l15;
  int rc0 = r0 < NSUB ? r0 : NSUB - 1;
  int rc1 = r1 < NSUB ? r1 : NSUB - 1;
  const float* A0 = adj + (size_t)s * NSUB * NSUB + (size_t)rc0 * NSUB;
  const float* A1 = adj + (size_t)s * NSUB * NSUB + (size_t)rc1 * NSUB;
  const short* B = Pt + (size_t)s * HID * NSUB;
  const short* B0 = B + (size_t)(l15) * NSUB;
  const short* B1 = B + (size_t)(16 + l15) * NSUB;
  const short* B2 = B + (size_t)(32 + l15) * NSUB;
  const short* B3 = B + (size_t)(48 + l15) * NSUB;

  f32x4 acc[2][4];
  #pragma unroll
  for (int f = 0; f < 2; ++f)
    #pragma unroll
    for (int nf = 0; nf < 4; ++nf) acc[f][nf] = (f32x4){0.f, 0.f, 0.f, 0.f};

  int kb = ks_ + g * 8;
  f32x4 a00 = __builtin_nontemporal_load((const f32x4*)(A0 + kb));
  f32x4 a01 = __builtin_nontemporal_load((const f32x4*)(A0 + kb + 4));
  f32x4 a10 = __builtin_nontemporal_load((const f32x4*)(A1 + kb));
  f32x4 a11 = __builtin_nontemporal_load((const f32x4*)(A1 + kb + 4));
  bf16x8 b0 = *(const bf16x8*)(B0 + kb);
  bf16x8 b1 = *(const bf16x8*)(B1 + kb);
  bf16x8 b2 = *(const bf16x8*)(B2 + kb);
  bf16x8 b3 = *(const bf16x8*)(B3 + kb);

  for (int k0 = ks_; k0 < ke_; k0 += 32) {
    int kn = k0 + 32;
    int kbn = (kn < ke_ ? kn : ks_) + g * 8;
    f32x4 n00 = __builtin_nontemporal_load((const f32x4*)(A0 + kbn));
    f32x4 n01 = __builtin_nontemporal_load((const f32x4*)(A0 + kbn + 4));
    f32x4 n10 = __builtin_nontemporal_load((const f32x4*)(A1 + kbn));
    f32x4 n11 = __builtin_nontemporal_load((const f32x4*)(A1 + kbn + 4));
    bf16x8 nb0 = *(const bf16x8*)(B0 + kbn);
    bf16x8 nb1 = *(const bf16x8*)(B1 + kbn);
    bf16x8 nb2 = *(const bf16x8*)(B2 + kbn);
    bf16x8 nb3 = *(const bf16x8*)(B3 + kbn);

    bf16x8 af0, af1;
    af0[0] = f2bf(a00.x); af0[1] = f2bf(a00.y); af0[2] = f2bf(a00.z); af0[3] = f2bf(a00.w);
    af0[4] = f2bf(a01.x); af0[5] = f2bf(a01.y); af0[6] = f2bf(a01.z); af0[7] = f2bf(a01.w);
    af1[0] = f2bf(a10.x); af1[1] = f2bf(a10.y); af1[2] = f2bf(a10.z); af1[3] = f2bf(a10.w);
    af1[4] = f2bf(a11.x); af1[5] = f2bf(a11.y); af1[6] = f2bf(a11.z); af1[7] = f2bf(a11.w);

    acc[0][0] = __builtin_amdgcn_mfma_f32_16x16x32_bf16(af0, b0, acc[0][0], 0, 0, 0);
    acc[0][1] = __builtin_amdgcn_mfma_f32_16x16x32_bf16(af0, b1, acc[0][1], 0, 0, 0);
    acc[0][2] = __builtin_amdgcn_mfma_f32_16x16x32_bf16(af0, b2, acc[0][2], 0, 0, 0);
    acc[0][3] = __builtin_amdgcn_mfma_f32_16x16x32_bf16(af0, b3, acc[0][3], 0, 0, 0);
    acc[1][0] = __builtin_amdgcn_mfma_f32_16x16x32_bf16(af1, b0, acc[1][0], 0, 0, 0);
    acc[1][1] = __builtin_amdgcn_mfma_f32_16x16x32_bf16(af1, b1, acc[1][1], 0, 0, 0);
    acc[1][2] = __builtin_amdgcn_mfma_f32_16x16x32_bf16(af1, b2, acc[1][2], 0, 0, 0);
    acc[1][3] = __builtin_amdgcn_mfma_f32_16x16x32_bf16(af1, b3, acc[1][3], 0, 0, 0);

    a00 = n00; a01 = n01; a10 = n10; a11 = n11;
    b0 = nb0; b1 = nb1; b2 = nb2; b3 = nb3;
  }

  float* P = part + (size_t)(z * S + s) * NSUB * HID;
  #pragma unroll
  for (int f = 0; f < 2; ++f)
    #pragma unroll
    for (int nf = 0; nf < 4; ++nf) {
      int col = nf * 16 + l15;
      #pragma unroll
      for (int r = 0; r < 4; ++r) {
        int row = m0 + f * 16 + g * 4 + r;
        if (row < NSUB) P[(size_t)row * HID + col] = acc[f][nf][r];
      }
    }
}

// ---------------- reduce layer-1 partials (x4) + bias + relu, fused h@W2 -> Pt2 (bf16 ^T)
__global__ __launch_bounds__(256) void k_reduce1(const float* __restrict__ part,
                                                 const float* __restrict__ b1,
                                                 const float* __restrict__ W2,
                                                 short* __restrict__ Pt2) {
  __shared__ float h[32][65];
  int bid = blockIdx.x;
  int s = bid / 125, i0 = (bid - s * 125) * 32;
  int t = threadIdx.x;
  int r = t >> 3, c8 = (t & 7) * 8;
  const size_t zs = (size_t)S * NSUB * HID;
  const float* P0 = part + ((size_t)s * NSUB + i0 + r) * HID + c8;
  #pragma unroll
  for (int u = 0; u < 8; ++u)
    h[r][c8 + u] = fmaxf(P0[u] + P0[zs + u] + P0[2*zs + u] + P0[3*zs + u] + b1[c8 + u], 0.f);
  __syncthreads();
  int j = t & 63, ib = t >> 6;
  float acc[8];
  #pragma unroll
  for (int u = 0; u < 8; ++u) acc[u] = 0.f;
  for (int k = 0; k < HID; ++k) {
    float w = W2[k * HID + j];
    #pragma unroll
    for (int u = 0; u < 8; ++u) acc[u] += h[ib * 8 + u][k] * w;
  }
  bf16x8 o;
  #pragma unroll
  for (int u = 0; u < 8; ++u) o[u] = f2bf(acc[u]);
  *(bf16x8*)(Pt2 + ((size_t)s * HID + j) * NSUB + i0 + ib * 8) = o;
}

// ---------------- reduce layer-2 partials (x4) + bias + relu -> H fp32
__global__ __launch_bounds__(256) void k_reduce2(const float* __restrict__ part,
                                                 const float* __restrict__ b2,
                                                 float* __restrict__ H) {
  size_t idx = ((size_t)blockIdx.x * 256 + threadIdx.x) * 8;
  const size_t zs = (size_t)S * NSUB * HID;
  const float* P0 = part + idx;
  int c = (int)(idx & 63);
  f32x4 r0, r1;
  #pragma unroll
  for (int u = 0; u < 4; ++u) {
    r0[u] = fmaxf(P0[u]     + P0[zs + u]     + P0[2*zs + u]     + P0[3*zs + u]     + b2[c + u], 0.f);
    r1[u] = fmaxf(P0[4 + u] + P0[zs + 4 + u] + P0[2*zs + 4 + u] + P0[3*zs + 4 + u] + b2[c + 4 + u], 0.f);
  }
  *(f32x4*)(H + idx) = r0;
  *(f32x4*)(H + idx + 4) = r1;
}

// ---------------- per-node attention over snapshots -> compact Zb (bf16)
__global__ __launch_bounds__(256) void k_attn(const float* __restrict__ H,
                                              const int* __restrict__ posIdx,
                                              const float* __restrict__ Wq, const float* __restrict__ bq,
                                              const float* __restrict__ Wk, const float* __restrict__ bk,
                                              const float* __restrict__ Wv, const float* __restrict__ bv,
                                              const float* __restrict__ Wo, const float* __restrict__ bo,
                                              const float* __restrict__ te,
                                              short* __restrict__ Zb) {
  __shared__ __align__(16) float xk[4][S][HID];
  __shared__ __align__(16) float qs[4][S][HID];
  __shared__ __align__(16) float ks[4][S][HID];
  __shared__ __align__(16) float vs[4][S][HID];
  __shared__ __align__(16) float os[4][S][HID];
  int w = threadIdx.x >> 6;
  int lane = threadIdx.x & 63;
  int n = blockIdx.x * 4 + w;
  int pi[S];
  #pragma unroll
  for (int s = 0; s < S; ++s) {
    pi[s] = posIdx[n * S + s];
    xk[w][s][lane] = (pi[s] >= 0) ? H[((size_t)s * NSUB + pi[s]) * HID + lane] : 0.f;
  }
  __syncthreads();
  float aq[S], ak[S], av[S];
  #pragma unroll
  for (int s = 0; s < S; ++s) { aq[s] = bq[lane]; ak[s] = bk[lane]; av[s] = bv[lane]; }
  for (int k = 0; k < HID; ++k) {
    float wq = Wq[k*HID + lane], wk_ = Wk[k*HID + lane], wv = Wv[k*HID + lane];
    #pragma unroll
    for (int s = 0; s < S; ++s) {
      float xv = xk[w][s][k];
      aq[s] += xv * wq; ak[s] += xv * wk_; av[s] += xv * wv;
    }
  }
  const float qscale = 0.35355339059327373f;
  #pragma unroll
  for (int s = 0; s < S; ++s) {
    qs[w][s][lane] = aq[s] * qscale;
    ks[w][s][lane] = ak[s];
    vs[w][s][lane] = av[s];
  }
  __syncthreads();
  int h = lane >> 3, sq = lane & 7;
  f32x4 q0 = *(const f32x4*)&qs[w][sq][h * DH];
  f32x4 q1 = *(const f32x4*)&qs[w][sq][h * DH + 4];
  float sc[S];
  #pragma unroll
  for (int t = 0; t < S; ++t) {
    f32x4 k0v = *(const f32x4*)&ks[w][t][h * DH];
    f32x4 k1v = *(const f32x4*)&ks[w][t][h * DH + 4];
    float d = q0.x*k0v.x + q0.y*k0v.y + q0.z*k0v.z + q0.w*k0v.w
            + q1.x*k1v.x + q1.y*k1v.y + q1.z*k1v.z + q1.w*k1v.w;
    sc[t] = d + te[(t - sq + S - 1) * NH + h];
  }
  float m = sc[0];
  #pragma unroll
  for (int t = 1; t < S; ++t) m = fmaxf(m, sc[t]);
  float sum = 0.f;
  #pragma unroll
  for (int t = 0; t < S; ++t) { sc[t] = expf(sc[t] - m); sum += sc[t]; }
  float inv = 1.f / sum;
  f32x4 o0 = (f32x4){0.f,0.f,0.f,0.f}, o1 = (f32x4){0.f,0.f,0.f,0.f};
  #pragma unroll
  for (int t = 0; t < S; ++t) {
    f32x4 v0 = *(const f32x4*)&vs[w][t][h * DH];
    f32x4 v1 = *(const f32x4*)&vs[w][t][h * DH + 4];
    #pragma unroll
    for (int u = 0; u < 4; ++u) { o0[u] += sc[t] * v0[u]; o1[u] += sc[t] * v1[u]; }
  }
  #pragma unroll
  for (int u = 0; u < 4; ++u) { o0[u] *= inv; o1[u] *= inv; }
  *(f32x4*)&os[w][sq][h * DH]     = o0;
  *(f32x4*)&os[w][sq][h * DH + 4] = o1;
  __syncthreads();
  float ao[S];
  #pragma unroll
  for (int s = 0; s < S; ++s) ao[s] = bo[lane];
  for (int k = 0; k < HID; ++k) {
    float wo = Wo[k*HID + lane];
    #pragma unroll
    for (int s = 0; s < S; ++s) ao[s] += os[w][s][k] * wo;
  }
  #pragma unroll
  for (int s = 0; s < S; ++s)
    if (pi[s] >= 0) Zb[((size_t)s * NSUB + pi[s]) * HID + lane] = f2bf(ao[s]);
}

// ---------------- out[s] = Z[s] @ Z[s]^T, XCD swizzle, LDS-transposed dwordx4 NT stores
__global__ __launch_bounds__(256) void k_dec(const short* __restrict__ Zb,
                                             float* __restrict__ out) {
  __shared__ __align__(16) float tr[4][16][68];
  int bid = blockIdx.x;
  int s = bid & 7;
  int tt = bid >> 3;
  int by = tt / 63, bx = tt - by * 63;
  int wave = threadIdx.x >> 6, lane = threadIdx.x & 63;
  int l15 = lane & 15, g = lane >> 4;
  int m0 = by * 64 + wave * 16;
  int n0 = bx * 64;
  const short* ZS = Zb + (size_t)s * NSUB * HID;
  int mrow = m0 + l15;
  int mc = mrow < NSUB ? mrow : NSUB - 1;
  bf16x8 a0 = *(const bf16x8*)(ZS + (size_t)mc * HID + g * 8);
  bf16x8 a1 = *(const bf16x8*)(ZS + (size_t)mc * HID + 32 + g * 8);
  f32x4 acc[4];
  #pragma unroll
  for (int nf = 0; nf < 4; ++nf) acc[nf] = (f32x4){0.f, 0.f, 0.f, 0.f};
  #pragma unroll
  for (int nf = 0; nf < 4; ++nf) {
    int ncol = n0 + nf * 16 + l15;
    int nc = ncol < NSUB ? ncol : NSUB - 1;
    bf16x8 b0 = *(const bf16x8*)(ZS + (size_t)nc * HID + g * 8);
    bf16x8 b1 = *(const bf16x8*)(ZS + (size_t)nc * HID + 32 + g * 8);
    acc[nf] = __builtin_amdgcn_mfma_f32_16x16x32_bf16(a0, b0, acc[nf], 0, 0, 0);
    acc[nf] = __builtin_amdgcn_mfma_f32_16x16x32_bf16(a1, b1, acc[nf], 0, 0, 0);
  }
  #pragma unroll
  for (int nf = 0; nf < 4; ++nf)
    #pragma unroll
    for (int r = 0; r < 4; ++r)
      tr[wave][g * 4 + r][nf * 16 + l15] = acc[nf][r];
  __syncthreads();
  float* outS = out + (size_t)s * NSUB * NSUB;
  #pragma unroll
  for (int p = 0; p < 4; ++p) {
    int rr = p * 4 + g;
    int grow = m0 + rr;
    int gcol = n0 + l15 * 4;
    f32x4 v = *(const f32x4*)&tr[wave][rr][l15 * 4];
    if (grow < NSUB && gcol < NSUB)
      __builtin_nontemporal_store(v, (f32x4*)(outS + (size_t)grow * NSUB + gcol));
  }
}

extern "C" void kernel_launch(void* const* d_in, const int* in_sizes, int n_in,
                              void* d_out, int out_size, void* d_ws, size_t ws_size,
                              hipStream_t stream) {
  const int*   nodes = (const int*)d_in[0];
  const float* adj   = (const float*)d_in[1];
  const float* emb   = (const float*)d_in[2];
  const float* W1    = (const float*)d_in[3];
  const float* b1    = (const float*)d_in[4];
  const float* W2    = (const float*)d_in[5];
  const float* b2    = (const float*)d_in[6];
  const float* te    = (const float*)d_in[7];
  const float* Wq    = (const float*)d_in[8];
  const float* bq    = (const float*)d_in[9];
  const float* Wk    = (const float*)d_in[10];
  const float* bk    = (const float*)d_in[11];
  const float* Wv    = (const float*)d_in[12];
  const float* bv    = (const float*)d_in[13];
  const float* Wo    = (const float*)d_in[14];
  const float* bo    = (const float*)d_in[15];
  float* outp = (float*)d_out;

  // ws: part 4x8MB | H 8MB | Pt 4MB | Zb 4MB | posIdx 0.64MB  (~49MB)
  float* part = (float*)d_ws;
  float* H    = part + 4 * (size_t)S * NSUB * HID;
  short* Pt   = (short*)(H + (size_t)S * NSUB * HID);
  short* Zb   = Pt + (size_t)S * HID * NSUB;
  int* posIdx = (int*)(Zb + (size_t)S * NSUB * HID);

  k_pos_init<<<(NTOT*S + 255)/256, 256, 0, stream>>>(posIdx);
  k_pos_scatter<<<(S*NSUB + 255)/256, 256, 0, stream>>>(nodes, posIdx);

  // GCN layer 1 (fused W2 in reduce)
  k_feat_w1<<<2000, 256, 0, stream>>>(nodes, emb, W1, Pt);
  k_adj<<<1024, 256, 0, stream>>>(adj, Pt, part);
  k_reduce1<<<1000, 256, 0, stream>>>(part, b1, W2, Pt);
  // GCN layer 2
  k_adj<<<1024, 256, 0, stream>>>(adj, Pt, part);
  k_reduce2<<<1000, 256, 0, stream>>>(part, b2, H);
  // attention -> compact Z (bf16)
  k_attn<<<NTOT/4, 256, 0, stream>>>(H, posIdx, Wq, bq, Wk, bk, Wv, bv, Wo, bo, te, Zb);
  // decoder
  k_dec<<<63*63*8, 256, 0, stream>>>(Zb, outp);
}

// Round 7
// 505.549 us; speedup vs baseline: 1.2339x; 1.2339x over previous
//
#include <hip/hip_runtime.h>
#include <hip/hip_bf16.h>
#include <cstdint>

#define S 8
#define NTOT 20000
#define NSUB 4000
#define F 128
#define HID 64
#define NH 8
#define DH 8
#define KSPL 2016   // split-K boundary: 2016 (63 steps) / 1984 (62 steps), BK=32

typedef __attribute__((ext_vector_type(8))) short bf16x8;
typedef __attribute__((ext_vector_type(4))) short bf16x4;
typedef __attribute__((ext_vector_type(4))) float f32x4;

__device__ __forceinline__ short f2bf(float f) {
  union { __hip_bfloat16 h; short s; } u;
  u.h = __float2bfloat16(f);
  return u.s;
}

__device__ __forceinline__ void gload16(const void* gsrc, void* ldst) {
  __builtin_amdgcn_global_load_lds(
      (const __attribute__((address_space(1))) void*)gsrc,
      (__attribute__((address_space(3))) void*)ldst, 16, 0, 0);
}

// ---------------- position map
__global__ void k_pos_init(int* __restrict__ posIdx) {
  int t = blockIdx.x * 256 + threadIdx.x;
  if (t < NTOT * S) posIdx[t] = -1;
}

__global__ void k_pos_scatter(const int* __restrict__ nodes, int* __restrict__ posIdx) {
  int t = blockIdx.x * 256 + threadIdx.x;
  if (t < S * NSUB) {
    int s = t / NSUB, i = t - s * NSUB;
    posIdx[nodes[t] * S + s] = i;
  }
}

// ---------------- Pt1 = (emb[nodes] @ W1)^T bf16
__global__ __launch_bounds__(256) void k_feat_w1(const int* __restrict__ nodes,
                                                 const float* __restrict__ emb,
                                                 const float* __restrict__ W1,
                                                 short* __restrict__ Pt) {
  __shared__ __align__(16) float feat[16][F];
  __shared__ float tr[64][17];
  int t = threadIdx.x;
  int s = blockIdx.x / 250;
  int i0 = (blockIdx.x - s * 250) * 16;
  int gr0 = blockIdx.x * 16;
  int lr = t >> 4, lc = (t & 15) * 8;
  int n = nodes[gr0 + lr];
  *(f32x4*)&feat[lr][lc]     = *(const f32x4*)(emb + (size_t)n * F + lc);
  *(f32x4*)&feat[lr][lc + 4] = *(const f32x4*)(emb + (size_t)n * F + lc + 4);
  __syncthreads();
  int j = t & 63, ig = t >> 6;
  float acc[4] = {0.f, 0.f, 0.f, 0.f};
  for (int k = 0; k < F; ++k) {
    float w = W1[k * HID + j];
    #pragma unroll
    for (int i = 0; i < 4; ++i) acc[i] += feat[ig * 4 + i][k] * w;
  }
  #pragma unroll
  for (int i = 0; i < 4; ++i) tr[j][ig * 4 + i] = acc[i];
  __syncthreads();
  int jr = t >> 2, seg = (t & 3) * 4;
  bf16x4 o;
  #pragma unroll
  for (int u = 0; u < 4; ++u) o[u] = f2bf(tr[jr][seg + u]);
  *(bf16x4*)(Pt + ((size_t)s * HID + jr) * NSUB + i0 + seg) = o;
}

// ---------------- adj GEMM: LDS-staged (global_load_lds w16), XOR-swizzled src, dbuf
// grid 1008: s=bid&7 (XCD), rest=bid>>3: z=rest&1, mb=rest>>1. block 256 = 4 waves.
// tile: BM=64 x N=64, BK=32.
__global__ __launch_bounds__(256) void k_adj(const float* __restrict__ adj,
                                             const short* __restrict__ Pt,
                                             float* __restrict__ part) {
  __shared__ __align__(16) float As[2][64 * 32];   // row*128B, chunk-swizzled, 8KB/buf
  __shared__ __align__(16) short Bs[2][64 * 32];   // col*64B, chunk-swizzled, 4KB/buf
  int bid = blockIdx.x;
  int s = bid & 7;
  int rest = bid >> 3;
  int z = rest & 1, mb = rest >> 1;
  int ks_ = z ? KSPL : 0, ke_ = z ? NSUB : KSPL;
  int tid = threadIdx.x;
  int w = tid >> 6, lane = tid & 63, l15 = lane & 15, g = lane >> 4;
  int m0 = mb * 64;
  const float* adjS = adj + (size_t)s * NSUB * NSUB;
  const short* PtS  = Pt  + (size_t)s * HID * NSUB;

  // ---- staging maps (per-thread global src; linear LDS dest = wave base + lane*16)
  // A: buffer row r (128B) holds chunks [c ^ (r&7)] ; thread tid stages
  //    row = p*32 + (tid>>3), chunk slot = tid&7  -> logical chunk = slot ^ (row&7)
  int arow0 = tid >> 3;
  int aslot = tid & 7;
  int r0g = m0 + arow0;        r0g = r0g < NSUB ? r0g : NSUB - 1;
  int r1g = m0 + 32 + arow0;   r1g = r1g < NSUB ? r1g : NSUB - 1;
  int c0 = aslot ^ (arow0 & 7);
  int c1 = aslot ^ ((32 + arow0) & 7);
  const float* asrc0 = adjS + (size_t)r0g * NSUB + c0 * 4;
  const float* asrc1 = adjS + (size_t)r1g * NSUB + c1 * 4;
  // B: buffer col c (64B) holds chunks [j ^ (c&3)] ; thread tid stages
  //    col = tid>>2, chunk slot = tid&3 -> logical chunk = slot ^ (col&3)
  int bcol  = tid >> 2;
  int bchunk = (tid & 3) ^ (bcol & 3);
  const short* bsrc0 = PtS + (size_t)bcol * NSUB + bchunk * 8;

  char* As0 = (char*)&As[0][0];
  char* Bs0 = (char*)&Bs[0][0];
  int wb = w * 1024;                       // wave's linear staging base

  // ---- fragment-read byte offsets (swizzled)
  int arow = w * 16 + l15;
  int fa0 = arow * 128 + (((g * 2)     ^ (arow & 7)) * 16);
  int fa1 = arow * 128 + (((g * 2 + 1) ^ (arow & 7)) * 16);
  int fb[4];
  #pragma unroll
  for (int nf = 0; nf < 4; ++nf) {
    int col = nf * 16 + l15;
    fb[nf] = col * 64 + ((g ^ (col & 3)) * 16);
  }

  f32x4 acc[4];
  #pragma unroll
  for (int nf = 0; nf < 4; ++nf) acc[nf] = (f32x4){0.f, 0.f, 0.f, 0.f};

  // prologue: stage first tile into buf 0
  gload16(asrc0 + ks_, As0 + 0    + wb);
  gload16(asrc1 + ks_, As0 + 4096 + wb);
  gload16(bsrc0 + ks_, Bs0 + wb);

  int nsteps = (ke_ - ks_) >> 5;
  for (int t = 0; t < nsteps; ++t) {
    __syncthreads();                 // drains vmcnt -> buf (t&1) ready; prior reads done
    int cur = t & 1;
    if (t + 1 < nsteps) {
      int kn = ks_ + (t + 1) * 32;
      int nb  = (cur ^ 1) * 8192;
      int nbs = (cur ^ 1) * 4096;
      gload16(asrc0 + kn, As0 + nb + 0    + wb);
      gload16(asrc1 + kn, As0 + nb + 4096 + wb);
      gload16(bsrc0 + kn, Bs0 + nbs + wb);
    }
    const char* Ab = As0 + cur * 8192;
    const char* Bb = Bs0 + cur * 4096;
    f32x4 a0 = *(const f32x4*)(Ab + fa0);
    f32x4 a1 = *(const f32x4*)(Ab + fa1);
    bf16x8 afr;
    afr[0] = f2bf(a0.x); afr[1] = f2bf(a0.y); afr[2] = f2bf(a0.z); afr[3] = f2bf(a0.w);
    afr[4] = f2bf(a1.x); afr[5] = f2bf(a1.y); afr[6] = f2bf(a1.z); afr[7] = f2bf(a1.w);
    bf16x8 b0 = *(const bf16x8*)(Bb + fb[0]);
    bf16x8 b1 = *(const bf16x8*)(Bb + fb[1]);
    bf16x8 b2 = *(const bf16x8*)(Bb + fb[2]);
    bf16x8 b3 = *(const bf16x8*)(Bb + fb[3]);
    acc[0] = __builtin_amdgcn_mfma_f32_16x16x32_bf16(afr, b0, acc[0], 0, 0, 0);
    acc[1] = __builtin_amdgcn_mfma_f32_16x16x32_bf16(afr, b1, acc[1], 0, 0, 0);
    acc[2] = __builtin_amdgcn_mfma_f32_16x16x32_bf16(afr, b2, acc[2], 0, 0, 0);
    acc[3] = __builtin_amdgcn_mfma_f32_16x16x32_bf16(afr, b3, acc[3], 0, 0, 0);
  }

  float* P = part + (size_t)(z * S + s) * NSUB * HID;
  #pragma unroll
  for (int nf = 0; nf < 4; ++nf) {
    int col = nf * 16 + l15;
    #pragma unroll
    for (int r = 0; r < 4; ++r) {
      int row = m0 + w * 16 + g * 4 + r;
      if (row < NSUB) P[(size_t)row * HID + col] = acc[nf][r];
    }
  }
}

// ---------------- reduce layer-1 partials (x2) + bias + relu, fused h@W2 -> Pt2 (bf16 ^T)
__global__ __launch_bounds__(256) void k_reduce1(const float* __restrict__ part,
                                                 const float* __restrict__ b1,
                                                 const float* __restrict__ W2,
                                                 short* __restrict__ Pt2) {
  __shared__ float h[32][65];
  int bid = blockIdx.x;
  int s = bid / 125, i0 = (bid - s * 125) * 32;
  int t = threadIdx.x;
  int r = t >> 3, c8 = (t & 7) * 8;
  const size_t zs = (size_t)S * NSUB * HID;
  const float* P0 = part + ((size_t)s * NSUB + i0 + r) * HID + c8;
  #pragma unroll
  for (int u = 0; u < 8; ++u)
    h[r][c8 + u] = fmaxf(P0[u] + P0[zs + u] + b1[c8 + u], 0.f);
  __syncthreads();
  int j = t & 63, ib = t >> 6;
  float acc[8];
  #pragma unroll
  for (int u = 0; u < 8; ++u) acc[u] = 0.f;
  for (int k = 0; k < HID; ++k) {
    float w = W2[k * HID + j];
    #pragma unroll
    for (int u = 0; u < 8; ++u) acc[u] += h[ib * 8 + u][k] * w;
  }
  bf16x8 o;
  #pragma unroll
  for (int u = 0; u < 8; ++u) o[u] = f2bf(acc[u]);
  *(bf16x8*)(Pt2 + ((size_t)s * HID + j) * NSUB + i0 + ib * 8) = o;
}

// ---------------- reduce layer-2 partials (x2) + bias + relu -> H fp32
__global__ __launch_bounds__(256) void k_reduce2(const float* __restrict__ part,
                                                 const float* __restrict__ b2,
                                                 float* __restrict__ H) {
  size_t idx = ((size_t)blockIdx.x * 256 + threadIdx.x) * 8;
  const size_t zs = (size_t)S * NSUB * HID;
  const float* P0 = part + idx;
  int c = (int)(idx & 63);
  f32x4 r0, r1;
  #pragma unroll
  for (int u = 0; u < 4; ++u) {
    r0[u] = fmaxf(P0[u]     + P0[zs + u]     + b2[c + u], 0.f);
    r1[u] = fmaxf(P0[4 + u] + P0[zs + 4 + u] + b2[c + 4 + u], 0.f);
  }
  *(f32x4*)(H + idx) = r0;
  *(f32x4*)(H + idx + 4) = r1;
}

// ---------------- per-node attention over snapshots -> compact Zb (bf16)
__global__ __launch_bounds__(256) void k_attn(const float* __restrict__ H,
                                              const int* __restrict__ posIdx,
                                              const float* __restrict__ Wq, const float* __restrict__ bq,
                                              const float* __restrict__ Wk, const float* __restrict__ bk,
                                              const float* __restrict__ Wv, const float* __restrict__ bv,
                                              const float* __restrict__ Wo, const float* __restrict__ bo,
                                              const float* __restrict__ te,
                                              short* __restrict__ Zb) {
  __shared__ __align__(16) float xk[4][S][HID];
  __shared__ __align__(16) float qs[4][S][HID];
  __shared__ __align__(16) float ks[4][S][HID];
  __shared__ __align__(16) float vs[4][S][HID];
  __shared__ __align__(16) float os[4][S][HID];
  int w = threadIdx.x >> 6;
  int lane = threadIdx.x & 63;
  int n = blockIdx.x * 4 + w;
  int pi[S];
  #pragma unroll
  for (int s = 0; s < S; ++s) {
    pi[s] = posIdx[n * S + s];
    xk[w][s][lane] = (pi[s] >= 0) ? H[((size_t)s * NSUB + pi[s]) * HID + lane] : 0.f;
  }
  __syncthreads();
  float aq[S], ak[S], av[S];
  #pragma unroll
  for (int s = 0; s < S; ++s) { aq[s] = bq[lane]; ak[s] = bk[lane]; av[s] = bv[lane]; }
  for (int k = 0; k < HID; ++k) {
    float wq = Wq[k*HID + lane], wk_ = Wk[k*HID + lane], wv = Wv[k*HID + lane];
    #pragma unroll
    for (int s = 0; s < S; ++s) {
      float xv = xk[w][s][k];
      aq[s] += xv * wq; ak[s] += xv * wk_; av[s] += xv * wv;
    }
  }
  const float qscale = 0.35355339059327373f;
  #pragma unroll
  for (int s = 0; s < S; ++s) {
    qs[w][s][lane] = aq[s] * qscale;
    ks[w][s][lane] = ak[s];
    vs[w][s][lane] = av[s];
  }
  __syncthreads();
  int h = lane >> 3, sq = lane & 7;
  f32x4 q0 = *(const f32x4*)&qs[w][sq][h * DH];
  f32x4 q1 = *(const f32x4*)&qs[w][sq][h * DH + 4];
  float sc[S];
  #pragma unroll
  for (int t = 0; t < S; ++t) {
    f32x4 k0v = *(const f32x4*)&ks[w][t][h * DH];
    f32x4 k1v = *(const f32x4*)&ks[w][t][h * DH + 4];
    float d = q0.x*k0v.x + q0.y*k0v.y + q0.z*k0v.z + q0.w*k0v.w
            + q1.x*k1v.x + q1.y*k1v.y + q1.z*k1v.z + q1.w*k1v.w;
    sc[t] = d + te[(t - sq + S - 1) * NH + h];
  }
  float m = sc[0];
  #pragma unroll
  for (int t = 1; t < S; ++t) m = fmaxf(m, sc[t]);
  float sum = 0.f;
  #pragma unroll
  for (int t = 0; t < S; ++t) { sc[t] = expf(sc[t] - m); sum += sc[t]; }
  float inv = 1.f / sum;
  f32x4 o0 = (f32x4){0.f,0.f,0.f,0.f}, o1 = (f32x4){0.f,0.f,0.f,0.f};
  #pragma unroll
  for (int t = 0; t < S; ++t) {
    f32x4 v0 = *(const f32x4*)&vs[w][t][h * DH];
    f32x4 v1 = *(const f32x4*)&vs[w][t][h * DH + 4];
    #pragma unroll
    for (int u = 0; u < 4; ++u) { o0[u] += sc[t] * v0[u]; o1[u] += sc[t] * v1[u]; }
  }
  #pragma unroll
  for (int u = 0; u < 4; ++u) { o0[u] *= inv; o1[u] *= inv; }
  *(f32x4*)&os[w][sq][h * DH]     = o0;
  *(f32x4*)&os[w][sq][h * DH + 4] = o1;
  __syncthreads();
  float ao[S];
  #pragma unroll
  for (int s = 0; s < S; ++s) ao[s] = bo[lane];
  for (int k = 0; k < HID; ++k) {
    float wo = Wo[k*HID + lane];
    #pragma unroll
    for (int s = 0; s < S; ++s) ao[s] += os[w][s][k] * wo;
  }
  #pragma unroll
  for (int s = 0; s < S; ++s)
    if (pi[s] >= 0) Zb[((size_t)s * NSUB + pi[s]) * HID + lane] = f2bf(ao[s]);
}

// ---------------- out[s] = Z[s] @ Z[s]^T, XCD swizzle, LDS-transposed dwordx4 NT stores
__global__ __launch_bounds__(256) void k_dec(const short* __restrict__ Zb,
                                             float* __restrict__ out) {
  __shared__ __align__(16) float tr[4][16][68];
  int bid = blockIdx.x;
  int s = bid & 7;
  int tt = bid >> 3;
  int by = tt / 63, bx = tt - by * 63;
  int wave = threadIdx.x >> 6, lane = threadIdx.x & 63;
  int l15 = lane & 15, g = lane >> 4;
  int m0 = by * 64 + wave * 16;
  int n0 = bx * 64;
  const short* ZS = Zb + (size_t)s * NSUB * HID;
  int mrow = m0 + l15;
  int mc = mrow < NSUB ? mrow : NSUB - 1;
  bf16x8 a0 = *(const bf16x8*)(ZS + (size_t)mc * HID + g * 8);
  bf16x8 a1 = *(const bf16x8*)(ZS + (size_t)mc * HID + 32 + g * 8);
  f32x4 acc[4];
  #pragma unroll
  for (int nf = 0; nf < 4; ++nf) acc[nf] = (f32x4){0.f, 0.f, 0.f, 0.f};
  #pragma unroll
  for (int nf = 0; nf < 4; ++nf) {
    int ncol = n0 + nf * 16 + l15;
    int nc = ncol < NSUB ? ncol : NSUB - 1;
    bf16x8 b0 = *(const bf16x8*)(ZS + (size_t)nc * HID + g * 8);
    bf16x8 b1 = *(const bf16x8*)(ZS + (size_t)nc * HID + 32 + g * 8);
    acc[nf] = __builtin_amdgcn_mfma_f32_16x16x32_bf16(a0, b0, acc[nf], 0, 0, 0);
    acc[nf] = __builtin_amdgcn_mfma_f32_16x16x32_bf16(a1, b1, acc[nf], 0, 0, 0);
  }
  #pragma unroll
  for (int nf = 0; nf < 4; ++nf)
    #pragma unroll
    for (int r = 0; r < 4; ++r)
      tr[wave][g * 4 + r][nf * 16 + l15] = acc[nf][r];
  __syncthreads();
  float* outS = out + (size_t)s * NSUB * NSUB;
  #pragma unroll
  for (int p = 0; p < 4; ++p) {
    int rr = p * 4 + g;
    int grow = m0 + rr;
    int gcol = n0 + l15 * 4;
    f32x4 v = *(const f32x4*)&tr[wave][rr][l15 * 4];
    if (grow < NSUB && gcol < NSUB)
      __builtin_nontemporal_store(v, (f32x4*)(outS + (size_t)grow * NSUB + gcol));
  }
}

extern "C" void kernel_launch(void* const* d_in, const int* in_sizes, int n_in,
                              void* d_out, int out_size, void* d_ws, size_t ws_size,
                              hipStream_t stream) {
  const int*   nodes = (const int*)d_in[0];
  const float* adj   = (const float*)d_in[1];
  const float* emb   = (const float*)d_in[2];
  const float* W1    = (const float*)d_in[3];
  const float* b1    = (const float*)d_in[4];
  const float* W2    = (const float*)d_in[5];
  const float* b2    = (const float*)d_in[6];
  const float* te    = (const float*)d_in[7];
  const float* Wq    = (const float*)d_in[8];
  const float* bq    = (const float*)d_in[9];
  const float* Wk    = (const float*)d_in[10];
  const float* bk    = (const float*)d_in[11];
  const float* Wv    = (const float*)d_in[12];
  const float* bv    = (const float*)d_in[13];
  const float* Wo    = (const float*)d_in[14];
  const float* bo    = (const float*)d_in[15];
  float* outp = (float*)d_out;

  // ws: part 2x8MB | H 8MB | Pt 4MB | Zb 4MB | posIdx 0.64MB  (~33MB)
  float* part = (float*)d_ws;
  float* H    = part + 2 * (size_t)S * NSUB * HID;
  short* Pt   = (short*)(H + (size_t)S * NSUB * HID);
  short* Zb   = Pt + (size_t)S * HID * NSUB;
  int* posIdx = (int*)(Zb + (size_t)S * NSUB * HID);

  k_pos_init<<<(NTOT*S + 255)/256, 256, 0, stream>>>(posIdx);
  k_pos_scatter<<<(S*NSUB + 255)/256, 256, 0, stream>>>(nodes, posIdx);

  // GCN layer 1 (fused W2 in reduce)
  k_feat_w1<<<2000, 256, 0, stream>>>(nodes, emb, W1, Pt);
  k_adj<<<1008, 256, 0, stream>>>(adj, Pt, part);
  k_reduce1<<<1000, 256, 0, stream>>>(part, b1, W2, Pt);
  // GCN layer 2
  k_adj<<<1008, 256, 0, stream>>>(adj, Pt, part);
  k_reduce2<<<1000, 256, 0, stream>>>(part, b2, H);
  // attention -> compact Z (bf16)
  k_attn<<<NTOT/4, 256, 0, stream>>>(H, posIdx, Wq, bq, Wk, bk, Wv, bv, Wo, bo, te, Zb);
  // decoder
  k_dec<<<63*63*8, 256, 0, stream>>>(Zb, outp);
}